// Round 2
// baseline (260.453 us; speedup 1.0000x reference)
//
#include <hip/hip_runtime.h>

// 8 stacked 3x3 same-pad convs on independent 3x3 images == one affine map
// out = A*x + c  (A: 9x9, c: 9), identical for all 4M rows.
// Kernel 1 composes A,c -> d_ws (re-run every call; ws is re-poisoned).
// Kernel 2: wave-autonomous streaming apply. 64-thread blocks (1 wave), each
// handles a 256-row tile (2304 floats = 576 float4 = 9216 B LDS). All LDS
// exchange is wave-local -> the s_barrier of __syncthreads is a HW no-op for
// single-wave workgroups; no inter-wave coupling. 9 float4 loads in flight
// per wave hides HBM latency.

// ---------------- Kernel 1: compose the affine map --------------------------
__global__ void compose_affine(const float* __restrict__ w,   // [8,3,3] flat
                               const float* __restrict__ b,   // [8]
                               float* __restrict__ aff)       // [90]: A(81), c(9)
{
    __shared__ float W[72];
    __shared__ float B[8];
    __shared__ float A[2][81];
    __shared__ float C[2][9];
    const int t = threadIdx.x;

    // One round-trip to global up front; the 8-layer loop then runs on LDS.
    if (t < 72) W[t] = w[t];
    if (t >= 72 && t < 80) B[t - 72] = b[t - 72];
    if (t < 81) A[0][t] = (t / 9 == t % 9) ? 1.0f : 0.0f;
    if (t < 9)  C[0][t] = 0.0f;
    __syncthreads();

    int cur = 0;
    for (int d = 0; d < 8; ++d) {
        if (t < 81) {
            const int i = t / 9, j = t % 9;
            const int r = i / 3, cc = i % 3;
            float acc = 0.0f;
            float accc = (j == 0) ? B[d] : 0.0f;
            #pragma unroll
            for (int k = 0; k < 9; ++k) {
                const int rr = k / 3, kc = k % 3;
                const int dr = rr - r + 1, dc = kc - cc + 1;
                float m = 0.0f;
                if (dr >= 0 && dr < 3 && dc >= 0 && dc < 3)
                    m = W[d * 9 + dr * 3 + dc];
                acc = fmaf(m, A[cur][k * 9 + j], acc);
                if (j == 0) accc = fmaf(m, C[cur][k], accc);
            }
            A[1 - cur][t] = acc;
            if (j == 0) C[1 - cur][i] = accc;
        }
        __syncthreads();
        cur = 1 - cur;
    }
    if (t < 81) aff[t] = A[cur][t];
    if (t < 9)  aff[81 + t] = C[cur][t];
}

// ---------------- Kernel 2: wave-autonomous affine apply --------------------
// Tile: 256 rows = 576 float4. Lane L loads float4 (L + 64j), j=0..8.
// Lane L computes rows L, L+64, L+128, L+192. Row read addr (9*row + j)*4B:
// bank = (9L + j) mod 32 -> 9 coprime 32 -> conflict-free per 32 lanes,
// 2-way across wave64 (free).
__global__ __launch_bounds__(64) void apply_affine(
    const float4* __restrict__ in4,
    const float*  __restrict__ aff,
    float4* __restrict__ out4,
    long long n_f4)
{
    __shared__ float tile[2304];   // 9216 B
    float4* __restrict__ t4 = (float4*)tile;
    const int L = threadIdx.x;
    const long long base = (long long)blockIdx.x * 576;

    // ---- stage in: 9 coalesced float4 loads, all in flight together ----
    float4 r[9];
    if (base + 576 <= n_f4) {
        #pragma unroll
        for (int j = 0; j < 9; ++j) r[j] = in4[base + L + (long long)j * 64];
    } else {
        #pragma unroll
        for (int j = 0; j < 9; ++j) {
            const long long g = base + L + (long long)j * 64;
            r[j] = (g < n_f4) ? in4[g] : float4{0, 0, 0, 0};
        }
    }
    #pragma unroll
    for (int j = 0; j < 9; ++j) t4[L + j * 64] = r[j];
    __syncthreads();   // single-wave wg: s_barrier is a HW no-op, just waitcnt

    // ---- compute 4 rows per lane, in place ----
    #pragma unroll
    for (int jr = 0; jr < 4; ++jr) {
        const int row = L + jr * 64;
        float xv[9];
        #pragma unroll
        for (int j = 0; j < 9; ++j) xv[j] = tile[row * 9 + j];
        float y[9];
        #pragma unroll
        for (int i = 0; i < 9; ++i) y[i] = aff[81 + i];
        #pragma unroll
        for (int k = 0; k < 9; ++k) {
            #pragma unroll
            for (int i = 0; i < 9; ++i)
                y[i] = fmaf(aff[i * 9 + k], xv[k], y[i]);   // aff -> SGPR (uniform)
        }
        #pragma unroll
        for (int j = 0; j < 9; ++j) tile[row * 9 + j] = y[j];
    }
    __syncthreads();

    // ---- stage out: 9 coalesced float4 stores ----
    #pragma unroll
    for (int j = 0; j < 9; ++j) r[j] = t4[L + j * 64];
    if (base + 576 <= n_f4) {
        #pragma unroll
        for (int j = 0; j < 9; ++j) out4[base + L + (long long)j * 64] = r[j];
    } else {
        #pragma unroll
        for (int j = 0; j < 9; ++j) {
            const long long g = base + L + (long long)j * 64;
            if (g < n_f4) out4[g] = r[j];
        }
    }
}

extern "C" void kernel_launch(void* const* d_in, const int* in_sizes, int n_in,
                              void* d_out, int out_size, void* d_ws, size_t ws_size,
                              hipStream_t stream) {
    const float* x = (const float*)d_in[0];   // [N,9] fp32
    const float* w = (const float*)d_in[1];   // [8,1,1,3,3] fp32
    const float* b = (const float*)d_in[2];   // [8] fp32
    float* out = (float*)d_out;
    float* aff = (float*)d_ws;                // 90 floats

    const long long n_elems = (long long)in_sizes[0];   // 36,000,000
    const long long n_f4    = n_elems / 4;              // 9,000,000
    const long long tiles   = (n_f4 + 575) / 576;       // 15,625

    compose_affine<<<1, 128, 0, stream>>>(w, b, aff);
    apply_affine<<<dim3((unsigned)tiles), dim3(64), 0, stream>>>(
        (const float4*)x, aff, (float4*)out, n_f4);
}

// Round 4
// 248.214 us; speedup vs baseline: 1.0493x; 1.0493x over previous
//
#include <hip/hip_runtime.h>

// 8 stacked 3x3 same-pad convs on independent 3x3 images == one affine map
// out = A*x + c (A: 9x9, c: 9). compose_affine builds it in d_ws each call;
// apply_affine streams 4M rows through it.
//
// R4: retry the R3 nt experiment with clang native vectors
// (__builtin_nontemporal_* rejects HIP_vector_type structs).

typedef float v4f __attribute__((ext_vector_type(4)));

// ---------------- Kernel 1: compose the affine map --------------------------
__global__ void compose_affine(const float* __restrict__ w,   // [8,3,3] flat
                               const float* __restrict__ b,   // [8]
                               float* __restrict__ aff)       // [90]: A(81), c(9)
{
    __shared__ float W[72];
    __shared__ float B[8];
    __shared__ float A[2][81];
    __shared__ float C[2][9];
    const int t = threadIdx.x;

    if (t < 72) W[t] = w[t];
    if (t >= 72 && t < 80) B[t - 72] = b[t - 72];
    if (t < 81) A[0][t] = (t / 9 == t % 9) ? 1.0f : 0.0f;
    if (t < 9)  C[0][t] = 0.0f;
    __syncthreads();

    int cur = 0;
    for (int d = 0; d < 8; ++d) {
        if (t < 81) {
            const int i = t / 9, j = t % 9;
            const int r = i / 3, cc = i % 3;
            float acc = 0.0f;
            float accc = (j == 0) ? B[d] : 0.0f;
            #pragma unroll
            for (int k = 0; k < 9; ++k) {
                const int rr = k / 3, kc = k % 3;
                const int dr = rr - r + 1, dc = kc - cc + 1;
                float m = 0.0f;
                if (dr >= 0 && dr < 3 && dc >= 0 && dc < 3)
                    m = W[d * 9 + dr * 3 + dc];
                acc = fmaf(m, A[cur][k * 9 + j], acc);
                if (j == 0) accc = fmaf(m, C[cur][k], accc);
            }
            A[1 - cur][t] = acc;
            if (j == 0) C[1 - cur][i] = accc;
        }
        __syncthreads();
        cur = 1 - cur;
    }
    if (t < 81) aff[t] = A[cur][t];
    if (t < 9)  aff[81 + t] = C[cur][t];
}

// ---------------- Kernel 2: wave-autonomous affine apply (nt streams) -------
// Tile: 256 rows = 576 v4f. Lane L loads v4f (L + 64j), j=0..8; computes rows
// L+64*jr; row read (9*row+j): 9 coprime 32 banks -> conflict-free/32 lanes.
__global__ __launch_bounds__(64) void apply_affine(
    const v4f* __restrict__ in4,
    const float* __restrict__ aff,
    v4f* __restrict__ out4,
    long long n_f4)
{
    __shared__ float tile[2304];   // 9216 B
    v4f* __restrict__ t4 = (v4f*)tile;
    const int L = threadIdx.x;
    const long long base = (long long)blockIdx.x * 576;

    // ---- stage in: 9 coalesced nt float4 loads, all in flight together ----
    v4f r[9];
    if (base + 576 <= n_f4) {
        #pragma unroll
        for (int j = 0; j < 9; ++j)
            r[j] = __builtin_nontemporal_load(in4 + base + L + (long long)j * 64);
    } else {
        #pragma unroll
        for (int j = 0; j < 9; ++j) {
            const long long g = base + L + (long long)j * 64;
            r[j] = (g < n_f4) ? __builtin_nontemporal_load(in4 + g) : (v4f)0.0f;
        }
    }
    #pragma unroll
    for (int j = 0; j < 9; ++j) t4[L + j * 64] = r[j];
    __syncthreads();   // single-wave wg: s_barrier is a HW no-op, just waitcnt

    // ---- compute 4 rows per lane, in place ----
    #pragma unroll
    for (int jr = 0; jr < 4; ++jr) {
        const int row = L + jr * 64;
        float xv[9];
        #pragma unroll
        for (int j = 0; j < 9; ++j) xv[j] = tile[row * 9 + j];
        float y[9];
        #pragma unroll
        for (int i = 0; i < 9; ++i) y[i] = aff[81 + i];
        #pragma unroll
        for (int k = 0; k < 9; ++k) {
            #pragma unroll
            for (int i = 0; i < 9; ++i)
                y[i] = fmaf(aff[i * 9 + k], xv[k], y[i]);   // aff -> SGPR (uniform)
        }
        #pragma unroll
        for (int j = 0; j < 9; ++j) tile[row * 9 + j] = y[j];
    }
    __syncthreads();

    // ---- stage out: 9 coalesced nt float4 stores ----
    #pragma unroll
    for (int j = 0; j < 9; ++j) r[j] = t4[L + j * 64];
    if (base + 576 <= n_f4) {
        #pragma unroll
        for (int j = 0; j < 9; ++j)
            __builtin_nontemporal_store(r[j], out4 + base + L + (long long)j * 64);
    } else {
        #pragma unroll
        for (int j = 0; j < 9; ++j) {
            const long long g = base + L + (long long)j * 64;
            if (g < n_f4) __builtin_nontemporal_store(r[j], out4 + g);
        }
    }
}

extern "C" void kernel_launch(void* const* d_in, const int* in_sizes, int n_in,
                              void* d_out, int out_size, void* d_ws, size_t ws_size,
                              hipStream_t stream) {
    const float* x = (const float*)d_in[0];   // [N,9] fp32
    const float* w = (const float*)d_in[1];   // [8,1,1,3,3] fp32
    const float* b = (const float*)d_in[2];   // [8] fp32
    float* out = (float*)d_out;
    float* aff = (float*)d_ws;                // 90 floats

    const long long n_elems = (long long)in_sizes[0];   // 36,000,000
    const long long n_f4    = n_elems / 4;              // 9,000,000
    const long long tiles   = (n_f4 + 575) / 576;       // 15,625 (exact)

    compose_affine<<<1, 128, 0, stream>>>(w, b, aff);
    apply_affine<<<dim3((unsigned)tiles), dim3(64), 0, stream>>>(
        (const v4f*)x, aff, (v4f*)out, n_f4);
}